// Round 9
// baseline (147.817 us; speedup 1.0000x reference)
//
#include <hip/hip_runtime.h>
#include <hip/hip_bf16.h>
#include <cstdint>
#include <cstddef>

#define I_F   1024
#define O_F   1024
#define BATCH 4096
#define KDIM  9216   // 9 * 1024 : j-major (j=0 base/swish, j=1..8 spline bases)
#define EPSC  1e-7f

typedef __bf16 bf16;
typedef __bf16 bf16x4 __attribute__((ext_vector_type(4)));
typedef __bf16 bf16x8 __attribute__((ext_vector_type(8)));
typedef float  f32x4  __attribute__((ext_vector_type(4)));
typedef float  f32x16 __attribute__((ext_vector_type(16)));

// ---------------------------------------------------------------------------
// Kernel 1: activations A[b][j*1024+i] = {swish(x), bases[0..7]}  (bf16)
// ---------------------------------------------------------------------------
__global__ __launch_bounds__(256) void act_kernel(const float* __restrict__ x,
                                                  const float* __restrict__ grid,
                                                  bf16* __restrict__ A) {
    int t  = blockIdx.x * 256 + threadIdx.x;     // 1,048,576 threads
    int b  = t >> 8;
    int i0 = (t & 255) << 2;
    f32x4 xv4 = *(const f32x4*)(x + (size_t)b * I_F + i0);

    float g[12];
#pragma unroll
    for (int j = 0; j < 12; ++j) g[j] = grid[j];
    float r1[11], r2[10], r3[9];
#pragma unroll
    for (int j = 0; j < 11; ++j) r1[j] = __builtin_amdgcn_rcpf(g[j + 1] - g[j] + EPSC);
#pragma unroll
    for (int j = 0; j < 10; ++j) r2[j] = __builtin_amdgcn_rcpf(g[j + 2] - g[j] + EPSC);
#pragma unroll
    for (int j = 0; j < 9;  ++j) r3[j] = __builtin_amdgcn_rcpf(g[j + 3] - g[j] + EPSC);

    float sw[4];
    float bs8[4][8];
#pragma unroll
    for (int e = 0; e < 4; ++e) {
        float xv = xv4[e];
        float bas[11];
#pragma unroll
        for (int j = 0; j < 11; ++j)
            bas[j] = (xv >= g[j] && xv < g[j + 1]) ? 1.0f : 0.0f;
#pragma unroll
        for (int j = 0; j < 10; ++j)
            bas[j] = (xv - g[j]) * r1[j] * bas[j] + (g[j + 2] - xv) * r1[j + 1] * bas[j + 1];
#pragma unroll
        for (int j = 0; j < 9; ++j)
            bas[j] = (xv - g[j]) * r2[j] * bas[j] + (g[j + 3] - xv) * r2[j + 1] * bas[j + 1];
#pragma unroll
        for (int j = 0; j < 8; ++j)
            bas[j] = (xv - g[j]) * r3[j] * bas[j] + (g[j + 4] - xv) * r3[j + 1] * bas[j + 1];
#pragma unroll
        for (int k = 0; k < 8; ++k) bs8[e][k] = bas[k];
        float sig = 1.0f / (1.0f + __expf(-xv));
        sw[e] = xv * sig;
    }

    bf16* outp = A + (size_t)b * KDIM + i0;
    *(bf16x4*)(outp) = (bf16x4){(bf16)sw[0], (bf16)sw[1], (bf16)sw[2], (bf16)sw[3]};
#pragma unroll
    for (int k = 0; k < 8; ++k)
        *(bf16x4*)(outp + (size_t)(k + 1) * 1024) =
            (bf16x4){(bf16)bs8[0][k], (bf16)bs8[1][k], (bf16)bs8[2][k], (bf16)bs8[3][k]};
}

// ---------------------------------------------------------------------------
// Kernel 2: Wt[o][j*1024+i] = { base_scaler[i,o], spline_weight[i,o,k]*spline_scaler[i,o] }
// ---------------------------------------------------------------------------
__global__ __launch_bounds__(256) void wprep_kernel(const float* __restrict__ w,
                                                    const float* __restrict__ ss,
                                                    const float* __restrict__ bs,
                                                    bf16* __restrict__ Wt) {
    int g = blockIdx.x * 256 + threadIdx.x;      // 1024 i * 128 o-groups = 131072
    int i  = g & 1023;
    int o0 = (g >> 10) << 3;                     // 8 o per thread
#pragma unroll
    for (int oo = 0; oo < 8; ++oo) {
        int o = o0 + oo;
        size_t io = (size_t)i * 1024 + o;
        float scale = ss[io];
        float base  = bs[io];
        const float* wp = w + io * 8;
        f32x4 w0 = *(const f32x4*)(wp);
        f32x4 w1 = *(const f32x4*)(wp + 4);

        bf16* outp = Wt + (size_t)o * KDIM + i;
        outp[0] = (bf16)base;
#pragma unroll
        for (int k = 0; k < 4; ++k) outp[(size_t)(k + 1) * 1024] = (bf16)(w0[k] * scale);
#pragma unroll
        for (int k = 0; k < 4; ++k) outp[(size_t)(k + 5) * 1024] = (bf16)(w1[k] * scale);
    }
}

// ---------------------------------------------------------------------------
// Kernel 3: GEMM  out = A(4096x9216) * Wt^T(1024x9216), bf16 MFMA 32x32x16.
// R9: R6's proven schedule ({vmcnt(N); barrier; 8 frag reads; stage; MFMA
// cluster}, counted vmcnt, loose compiler interleave, setprio) at a
// 128x256 tile geometry: 128 tiles x split4 = 512 blocks = 2 blocks/CU
// (m114 implicit cross-block overlap covers barrier drains).
// Triple-buffered LDS 72KB (24KB/slot), depth-2, steady vmcnt(3).
// 8 waves 2Mx4N -> per-wave 64x64, acc f32x16[2][2] (64 VGPR).
// ---------------------------------------------------------------------------
__device__ __forceinline__ void load_lds16(const bf16* g, bf16* l) {
    __builtin_amdgcn_global_load_lds(
        (__attribute__((address_space(1))) void*)g,
        (__attribute__((address_space(3))) void*)l, 16, 0, 0);
}

__global__ __launch_bounds__(512, 4) void gemm_kernel(const bf16* __restrict__ A,
                                                      const bf16* __restrict__ Wt,
                                                      float* __restrict__ out,
                                                      bf16* __restrict__ parts,
                                                      int split, int ktiles) {  // BK=32 units
    __shared__ __align__(16) bf16 SA[3][4096];   // 3 slots x 8KB  (128 rows x 32 k)
    __shared__ __align__(16) bf16 SB[3][8192];   // 3 slots x 16KB (256 rows x 32 k)

    const int t    = threadIdx.x;
    const int lane = t & 63;
    const int w    = t >> 6;           // 0..7

    // XCD-chunked decode: 512 blocks, 64 per XCD; within an XCD same tn,
    // same s for 32-block runs (adjacent tm share the Wt (tn,s) L2 panel).
    const int nwg8 = gridDim.x >> 3;
    const int L    = (blockIdx.x & 7) * nwg8 + (blockIdx.x >> 3);
    const int nper = split << 5;       // 32 tm * split per tn
    const int tn   = L / nper;
    const int rem  = L - tn * nper;
    const int s    = rem >> 5;         // split index
    const int tm   = rem & 31;

    const int row0 = tm << 7;          // 128-row tile
    const int col0 = tn << 8;          // 256-col tile
    const size_t k0 = (size_t)s * ktiles * 32;

    // ---- staging (linear LDS dest; pre-swizzled global source) ----
    // Each DMA instr covers 16 rows x 4 16B-units; lane l -> row +(l>>2), unit l&3.
    // content(phys p, row r) = logical unit p ^ ((r>>1)&3).
    const int sr = lane >> 2;                         // 0..15
    const int lc = (lane & 3) ^ ((lane >> 3) & 3);    // pre-swizzled 16B-unit
    const bf16* gA0 = A  + (size_t)(row0 + w * 16 + sr) * KDIM + k0 + lc * 8;
    const bf16* gB0 = Wt + (size_t)(col0 + w * 32 + sr) * KDIM + k0 + lc * 8;

    // ---- fragment read coords ----
    const int wm  = w >> 2;            // 0..1  (M half: 64 rows each)
    const int wn  = w & 3;             // 0..3  (N quarter: 64 cols each)
    const int r31 = lane & 31;
    const int hi  = lane >> 5;
    const int swb = (r31 >> 1) & 3;    // read-side swizzle (row bits 1-2)

    f32x16 acc[2][2];
#pragma unroll
    for (int mt = 0; mt < 2; ++mt)
#pragma unroll
        for (int nt = 0; nt < 2; ++nt)
#pragma unroll
            for (int r = 0; r < 16; ++r) acc[mt][nt][r] = 0.f;

    auto stage = [&](int j) {
        const int sl = j % 3;
        const bf16* pa = gA0 + (size_t)j * 32;
        const bf16* pb = gB0 + (size_t)j * 32;
        load_lds16(pa,                     &SA[sl][w * 512]);            // A rows w*16..+16
        load_lds16(pb,                     &SB[sl][w * 1024]);           // B rows w*32..+16
        load_lds16(pb + (size_t)16 * KDIM, &SB[sl][w * 1024 + 512]);     // B rows +16..+32
    };

    auto compute = [&](int sl) {
        bf16x8 af[2][2], bv[2][2];
#pragma unroll
        for (int mt = 0; mt < 2; ++mt)
#pragma unroll
            for (int ks = 0; ks < 2; ++ks)
                af[mt][ks] = *(const bf16x8*)&SA[sl][(wm * 64 + mt * 32 + r31) * 32
                                                     + (((ks * 2 + hi) ^ swb) << 3)];
#pragma unroll
        for (int nt = 0; nt < 2; ++nt)
#pragma unroll
            for (int ks = 0; ks < 2; ++ks)
                bv[nt][ks] = *(const bf16x8*)&SB[sl][(wn * 64 + nt * 32 + r31) * 32
                                                     + (((ks * 2 + hi) ^ swb) << 3)];
        __builtin_amdgcn_s_setprio(1);
#pragma unroll
        for (int ks = 0; ks < 2; ++ks)
#pragma unroll
            for (int mt = 0; mt < 2; ++mt)
#pragma unroll
                for (int nt = 0; nt < 2; ++nt)
                    acc[mt][nt] = __builtin_amdgcn_mfma_f32_32x32x16_bf16(
                        af[mt][ks], bv[nt][ks], acc[mt][nt], 0, 0, 0);
        __builtin_amdgcn_s_setprio(0);
    };

    // Prologue: 2 K-tiles in flight (3 loads each).
    stage(0); stage(1);

    int j = 0;
    for (; j < ktiles - 2; ++j) {
        asm volatile("s_waitcnt vmcnt(3)" ::: "memory");   // tile j landed; j+1 in flight
        __builtin_amdgcn_s_barrier();                      // all waves done with slot j-1
        asm volatile("" ::: "memory");
        stage(j + 2);                                      // into slot freed at j-1
        compute(j % 3);
    }
    asm volatile("s_waitcnt vmcnt(3)" ::: "memory");
    __builtin_amdgcn_s_barrier();
    asm volatile("" ::: "memory");
    compute(j % 3); ++j;
    asm volatile("s_waitcnt vmcnt(0)" ::: "memory");
    __builtin_amdgcn_s_barrier();
    asm volatile("" ::: "memory");
    compute(j % 3);

    // Epilogue: 32x32 C/D layout: col=lane&31, row=(reg&3)+8*(reg>>2)+4*(lane>>5) [m74/m101]
    if (s == 0) {
        float* cp = out + (size_t)(row0 + wm * 64) * O_F + col0 + wn * 64 + r31;
#pragma unroll
        for (int mt = 0; mt < 2; ++mt)
#pragma unroll
            for (int nt = 0; nt < 2; ++nt)
#pragma unroll
                for (int r = 0; r < 16; ++r) {
                    int rl = (r & 3) + 8 * (r >> 2) + 4 * hi;
                    cp[(size_t)(mt * 32 + rl) * O_F + nt * 32] = acc[mt][nt][r];
                }
    } else {
        bf16* cp = parts + (size_t)(s - 1) * BATCH * O_F
                 + (size_t)(row0 + wm * 64) * O_F + col0 + wn * 64 + r31;
#pragma unroll
        for (int mt = 0; mt < 2; ++mt)
#pragma unroll
            for (int nt = 0; nt < 2; ++nt)
#pragma unroll
                for (int r = 0; r < 16; ++r) {
                    int rl = (r & 3) + 8 * (r >> 2) + 4 * hi;
                    cp[(size_t)(mt * 32 + rl) * O_F + nt * 32] = (bf16)acc[mt][nt][r];
                }
    }
}

// ---------------------------------------------------------------------------
// Kernel 4: out += sum(parts[0..np))   (split-K reduce), bf16 partials
// ---------------------------------------------------------------------------
__global__ __launch_bounds__(256) void add_kernel(float* __restrict__ out,
                                                  const bf16* __restrict__ parts,
                                                  int np) {
    int t = blockIdx.x * 256 + threadIdx.x;      // 1,048,576 threads, 4 f32 each
    f32x4 a = *((const f32x4*)out + t);
    for (int p = 0; p < np; ++p) {
        bf16x4 b = *((const bf16x4*)(parts + (size_t)p * BATCH * O_F) + t);
#pragma unroll
        for (int e = 0; e < 4; ++e) a[e] += (float)b[e];
    }
    *((f32x4*)out + t) = a;
}

// ---------------------------------------------------------------------------
extern "C" void kernel_launch(void* const* d_in, const int* in_sizes, int n_in,
                              void* d_out, int out_size, void* d_ws, size_t ws_size,
                              hipStream_t stream) {
    const float* x    = (const float*)d_in[0];
    const float* grid = (const float*)d_in[1];
    const float* w    = (const float*)d_in[2];
    const float* ss   = (const float*)d_in[3];
    const float* bs   = (const float*)d_in[4];
    float* out = (float*)d_out;

    const size_t nA = (size_t)BATCH * KDIM * 2;   // 75.5 MB
    const size_t nW = (size_t)O_F   * KDIM * 2;   // 18.9 MB
    const size_t nP = (size_t)BATCH * O_F  * 2;   // 8.39 MB per bf16 partial

    bf16* A  = (bf16*)d_ws;
    bf16* Wt = (bf16*)((char*)d_ws + nA);
    bf16* parts = (bf16*)((char*)d_ws + nA + nW);

    act_kernel<<<(BATCH * I_F / 4) / 256, 256, 0, stream>>>(x, grid, A);
    wprep_kernel<<<(I_F * O_F / 8) / 256, 256, 0, stream>>>(w, ss, bs, Wt);

    int split = (ws_size >= nA + nW + 3 * nP) ? 4
              : (ws_size >= nA + nW + nP)     ? 2 : 1;
    // 128 tiles (32 tm x 4 tn) x split blocks; ktiles (BK=32) = 288/split
    gemm_kernel<<<128 * split, 512, 0, stream>>>(A, Wt, out, parts, split, 288 / split);
    if (split > 1)
        add_kernel<<<(BATCH * O_F / 4) / 256, 256, 0, stream>>>(out, parts, split - 1);
}

// Round 10
// 146.422 us; speedup vs baseline: 1.0095x; 1.0095x over previous
//
#include <hip/hip_runtime.h>
#include <hip/hip_bf16.h>
#include <cstdint>
#include <cstddef>

#define I_F   1024
#define O_F   1024
#define BATCH 4096
#define KDIM  9216   // 9 * 1024 : j-major (j=0 base/swish, j=1..8 spline bases)
#define EPSC  1e-7f

typedef __bf16 bf16;
typedef __bf16 bf16x4 __attribute__((ext_vector_type(4)));
typedef __bf16 bf16x8 __attribute__((ext_vector_type(8)));
typedef float  f32x4  __attribute__((ext_vector_type(4)));
typedef float  f32x16 __attribute__((ext_vector_type(16)));

// ---------------------------------------------------------------------------
// Kernel 1: activations A[b][j*1024+i] = {swish(x), bases[0..7]}  (bf16)
// ---------------------------------------------------------------------------
__global__ __launch_bounds__(256) void act_kernel(const float* __restrict__ x,
                                                  const float* __restrict__ grid,
                                                  bf16* __restrict__ A) {
    int t  = blockIdx.x * 256 + threadIdx.x;     // 1,048,576 threads
    int b  = t >> 8;
    int i0 = (t & 255) << 2;
    f32x4 xv4 = *(const f32x4*)(x + (size_t)b * I_F + i0);

    float g[12];
#pragma unroll
    for (int j = 0; j < 12; ++j) g[j] = grid[j];
    float r1[11], r2[10], r3[9];
#pragma unroll
    for (int j = 0; j < 11; ++j) r1[j] = __builtin_amdgcn_rcpf(g[j + 1] - g[j] + EPSC);
#pragma unroll
    for (int j = 0; j < 10; ++j) r2[j] = __builtin_amdgcn_rcpf(g[j + 2] - g[j] + EPSC);
#pragma unroll
    for (int j = 0; j < 9;  ++j) r3[j] = __builtin_amdgcn_rcpf(g[j + 3] - g[j] + EPSC);

    float sw[4];
    float bs8[4][8];
#pragma unroll
    for (int e = 0; e < 4; ++e) {
        float xv = xv4[e];
        float bas[11];
#pragma unroll
        for (int j = 0; j < 11; ++j)
            bas[j] = (xv >= g[j] && xv < g[j + 1]) ? 1.0f : 0.0f;
#pragma unroll
        for (int j = 0; j < 10; ++j)
            bas[j] = (xv - g[j]) * r1[j] * bas[j] + (g[j + 2] - xv) * r1[j + 1] * bas[j + 1];
#pragma unroll
        for (int j = 0; j < 9; ++j)
            bas[j] = (xv - g[j]) * r2[j] * bas[j] + (g[j + 3] - xv) * r2[j + 1] * bas[j + 1];
#pragma unroll
        for (int j = 0; j < 8; ++j)
            bas[j] = (xv - g[j]) * r3[j] * bas[j] + (g[j + 4] - xv) * r3[j + 1] * bas[j + 1];
#pragma unroll
        for (int k = 0; k < 8; ++k) bs8[e][k] = bas[k];
        float sig = 1.0f / (1.0f + __expf(-xv));
        sw[e] = xv * sig;
    }

    bf16* outp = A + (size_t)b * KDIM + i0;
    *(bf16x4*)(outp) = (bf16x4){(bf16)sw[0], (bf16)sw[1], (bf16)sw[2], (bf16)sw[3]};
#pragma unroll
    for (int k = 0; k < 8; ++k)
        *(bf16x4*)(outp + (size_t)(k + 1) * 1024) =
            (bf16x4){(bf16)bs8[0][k], (bf16)bs8[1][k], (bf16)bs8[2][k], (bf16)bs8[3][k]};
}

// ---------------------------------------------------------------------------
// Kernel 2: Wt[o][j*1024+i] = { base_scaler[i,o], spline_weight[i,o,k]*spline_scaler[i,o] }
// ---------------------------------------------------------------------------
__global__ __launch_bounds__(256) void wprep_kernel(const float* __restrict__ w,
                                                    const float* __restrict__ ss,
                                                    const float* __restrict__ bs,
                                                    bf16* __restrict__ Wt) {
    int g = blockIdx.x * 256 + threadIdx.x;      // 1024 i * 128 o-groups = 131072
    int i  = g & 1023;
    int o0 = (g >> 10) << 3;                     // 8 o per thread
#pragma unroll
    for (int oo = 0; oo < 8; ++oo) {
        int o = o0 + oo;
        size_t io = (size_t)i * 1024 + o;
        float scale = ss[io];
        float base  = bs[io];
        const float* wp = w + io * 8;
        f32x4 w0 = *(const f32x4*)(wp);
        f32x4 w1 = *(const f32x4*)(wp + 4);

        bf16* outp = Wt + (size_t)o * KDIM + i;
        outp[0] = (bf16)base;
#pragma unroll
        for (int k = 0; k < 4; ++k) outp[(size_t)(k + 1) * 1024] = (bf16)(w0[k] * scale);
#pragma unroll
        for (int k = 0; k < 4; ++k) outp[(size_t)(k + 5) * 1024] = (bf16)(w1[k] * scale);
    }
}

// ---------------------------------------------------------------------------
// Kernel 3: GEMM  out = A(4096x9216) * Wt^T(1024x9216), bf16 MFMA 32x32x16.
// R10 = R6's proven 86us kernel VERBATIM (256x256 tile, 8 waves 2Mx4N, BK=32,
// quad-buffer 128KB LDS, counted vmcnt(8) depth-3, 1 barrier/K-tile,
// {12 frag ds_reads -> stage -> 16-MFMA cluster} loose compiler schedule,
// setprio, corrected 2-bit swizzle pair) -- only the epilogue now writes
// bf16 partials for s>0 (R8-proven, halves split-K traffic).
// ---------------------------------------------------------------------------
__device__ __forceinline__ void load_lds16(const bf16* g, bf16* l) {
    __builtin_amdgcn_global_load_lds(
        (__attribute__((address_space(1))) void*)g,
        (__attribute__((address_space(3))) void*)l, 16, 0, 0);
}

__global__ __launch_bounds__(512, 2) void gemm_kernel(const bf16* __restrict__ A,
                                                      const bf16* __restrict__ Wt,
                                                      float* __restrict__ out,
                                                      bf16* __restrict__ parts,
                                                      int split, int ktiles) {  // BK=32 units
    __shared__ __align__(16) bf16 SA[4][8192];   // 4 slots x 16KB (256 rows x 32 k)
    __shared__ __align__(16) bf16 SB[4][8192];

    const int t    = threadIdx.x;
    const int lane = t & 63;
    const int w    = t >> 6;           // 0..7

    // XCD-chunked decode: each XCD owns a contiguous L-range sharing one tn panel.
    const int nwg8 = gridDim.x >> 3;
    const int L    = (blockIdx.x & 7) * nwg8 + (blockIdx.x >> 3);
    const int nper = split << 4;
    const int tn   = L / nper;
    const int rem  = L - tn * nper;
    const int s    = rem >> 4;
    const int tm   = rem & 15;

    const int row0 = tm << 8;
    const int col0 = tn << 8;
    const size_t k0 = (size_t)s * ktiles * 32;

    // ---- staging (linear LDS dest; pre-swizzled global source) ----
    // content(phys unit p, row r) = logical unit p ^ ((r>>1)&3)
    const int sr = lane >> 2;                         // 0..15
    const int lc = (lane & 3) ^ ((lane >> 3) & 3);    // pre-swizzled 16B-unit
    const bf16* gA0 = A  + (size_t)(row0 + w * 16 + sr) * KDIM + k0 + lc * 8;
    const bf16* gB0 = Wt + (size_t)(col0 + w * 16 + sr) * KDIM + k0 + lc * 8;

    // ---- fragment read coords ----
    const int wm  = w >> 2;            // 0..1  (M half: 128 rows)
    const int wn  = w & 3;             // 0..3  (N quarter: 64 cols)
    const int r31 = lane & 31;
    const int hi  = lane >> 5;
    const int swb = (r31 >> 1) & 3;    // read-side swizzle (row bits 1-2)

    f32x16 acc[4][2];
#pragma unroll
    for (int mt = 0; mt < 4; ++mt)
#pragma unroll
        for (int nt = 0; nt < 2; ++nt)
#pragma unroll
            for (int r = 0; r < 16; ++r) acc[mt][nt][r] = 0.f;

    auto stage = [&](int j) {
        const int sl = j & 3;
        const bf16* pa = gA0 + (size_t)j * 32;
        const bf16* pb = gB0 + (size_t)j * 32;
        load_lds16(pa,                      &SA[sl][w * 512]);
        load_lds16(pa + (size_t)128 * KDIM, &SA[sl][4096 + w * 512]);
        load_lds16(pb,                      &SB[sl][w * 512]);
        load_lds16(pb + (size_t)128 * KDIM, &SB[sl][4096 + w * 512]);
    };

    auto compute = [&](int sl) {
        bf16x8 af[4][2], bfv[2][2];
#pragma unroll
        for (int mt = 0; mt < 4; ++mt)
#pragma unroll
            for (int ks = 0; ks < 2; ++ks)
                af[mt][ks] = *(const bf16x8*)&SA[sl][(wm * 128 + mt * 32 + r31) * 32
                                                    + (((ks * 2 + hi) ^ swb) << 3)];
#pragma unroll
        for (int nt = 0; nt < 2; ++nt)
#pragma unroll
            for (int ks = 0; ks < 2; ++ks)
                bfv[nt][ks] = *(const bf16x8*)&SB[sl][(wn * 64 + nt * 32 + r31) * 32
                                                     + (((ks * 2 + hi) ^ swb) << 3)];
        __builtin_amdgcn_s_setprio(1);
#pragma unroll
        for (int ks = 0; ks < 2; ++ks)
#pragma unroll
            for (int mt = 0; mt < 4; ++mt)
#pragma unroll
                for (int nt = 0; nt < 2; ++nt)
                    acc[mt][nt] = __builtin_amdgcn_mfma_f32_32x32x16_bf16(
                        af[mt][ks], bfv[nt][ks], acc[mt][nt], 0, 0, 0);
        __builtin_amdgcn_s_setprio(0);
    };

    // Prologue: 3 K-tiles in flight.
    stage(0); stage(1); stage(2);

    int j = 0;
    for (; j < ktiles - 3; ++j) {
        asm volatile("s_waitcnt vmcnt(8)" ::: "memory");   // tile j landed
        __builtin_amdgcn_s_barrier();                      // all waves see tile j
        asm volatile("" ::: "memory");
        stage(j + 3);                                      // slot freed at phase j-1
        compute(j & 3);
    }
    asm volatile("s_waitcnt vmcnt(8)" ::: "memory");
    __builtin_amdgcn_s_barrier();
    asm volatile("" ::: "memory");
    compute(j & 3); ++j;
    asm volatile("s_waitcnt vmcnt(4)" ::: "memory");
    __builtin_amdgcn_s_barrier();
    asm volatile("" ::: "memory");
    compute(j & 3); ++j;
    asm volatile("s_waitcnt vmcnt(0)" ::: "memory");
    __builtin_amdgcn_s_barrier();
    asm volatile("" ::: "memory");
    compute(j & 3);

    // Epilogue: 32x32 C/D layout: col=lane&31, row=(reg&3)+8*(reg>>2)+4*(lane>>5) [m74/m101]
    if (s == 0) {
        float* cp = out + (size_t)(row0 + wm * 128) * O_F + col0 + wn * 64 + r31;
#pragma unroll
        for (int mt = 0; mt < 4; ++mt)
#pragma unroll
            for (int nt = 0; nt < 2; ++nt)
#pragma unroll
                for (int r = 0; r < 16; ++r) {
                    int rl = (r & 3) + 8 * (r >> 2) + 4 * hi;
                    cp[(size_t)(mt * 32 + rl) * O_F + nt * 32] = acc[mt][nt][r];
                }
    } else {
        bf16* cp = parts + (size_t)(s - 1) * BATCH * O_F
                 + (size_t)(row0 + wm * 128) * O_F + col0 + wn * 64 + r31;
#pragma unroll
        for (int mt = 0; mt < 4; ++mt)
#pragma unroll
            for (int nt = 0; nt < 2; ++nt)
#pragma unroll
                for (int r = 0; r < 16; ++r) {
                    int rl = (r & 3) + 8 * (r >> 2) + 4 * hi;
                    cp[(size_t)(mt * 32 + rl) * O_F + nt * 32] = (bf16)acc[mt][nt][r];
                }
    }
}

// ---------------------------------------------------------------------------
// Kernel 4: out += sum(parts[0..np))   (split-K reduce), bf16 partials
// ---------------------------------------------------------------------------
__global__ __launch_bounds__(256) void add_kernel(float* __restrict__ out,
                                                  const bf16* __restrict__ parts,
                                                  int np) {
    int t = blockIdx.x * 256 + threadIdx.x;      // 1,048,576 threads, 4 f32 each
    f32x4 a = *((const f32x4*)out + t);
    for (int p = 0; p < np; ++p) {
        bf16x4 b = *((const bf16x4*)(parts + (size_t)p * BATCH * O_F) + t);
#pragma unroll
        for (int e = 0; e < 4; ++e) a[e] += (float)b[e];
    }
    *((f32x4*)out + t) = a;
}

// ---------------------------------------------------------------------------
extern "C" void kernel_launch(void* const* d_in, const int* in_sizes, int n_in,
                              void* d_out, int out_size, void* d_ws, size_t ws_size,
                              hipStream_t stream) {
    const float* x    = (const float*)d_in[0];
    const float* grid = (const float*)d_in[1];
    const float* w    = (const float*)d_in[2];
    const float* ss   = (const float*)d_in[3];
    const float* bs   = (const float*)d_in[4];
    float* out = (float*)d_out;

    const size_t nA = (size_t)BATCH * KDIM * 2;   // 75.5 MB
    const size_t nW = (size_t)O_F   * KDIM * 2;   // 18.9 MB
    const size_t nP = (size_t)BATCH * O_F  * 2;   // 8.39 MB per bf16 partial

    bf16* A  = (bf16*)d_ws;
    bf16* Wt = (bf16*)((char*)d_ws + nA);
    bf16* parts = (bf16*)((char*)d_ws + nA + nW);

    act_kernel<<<(BATCH * I_F / 4) / 256, 256, 0, stream>>>(x, grid, A);
    wprep_kernel<<<(I_F * O_F / 8) / 256, 256, 0, stream>>>(w, ss, bs, Wt);

    int split = (ws_size >= nA + nW + 3 * nP) ? 4
              : (ws_size >= nA + nW + nP)     ? 2 : 1;
    gemm_kernel<<<64 * split, 512, 0, stream>>>(A, Wt, out, parts, split, 288 / split);
    if (split > 1)
        add_kernel<<<(BATCH * O_F / 4) / 256, 256, 0, stream>>>(out, parts, split - 1);
}

// Round 11
// 129.070 us; speedup vs baseline: 1.1452x; 1.1344x over previous
//
#include <hip/hip_runtime.h>
#include <hip/hip_bf16.h>
#include <cstdint>
#include <cstddef>

#define I_F   1024
#define O_F   1024
#define BATCH 4096
#define KDIM  9216   // 9 * 1024 : j-major (j=0 base/swish, j=1..8 spline bases)
#define EPSC  1e-7f

typedef __bf16 bf16;
typedef __bf16 bf16x4 __attribute__((ext_vector_type(4)));
typedef __bf16 bf16x8 __attribute__((ext_vector_type(8)));
typedef float  f32x4  __attribute__((ext_vector_type(4)));
typedef float  f32x16 __attribute__((ext_vector_type(16)));

// ---------------------------------------------------------------------------
// Kernel 1: activations A[b][j*1024+i] = {swish(x), bases[0..7]}  (bf16)
// ---------------------------------------------------------------------------
__global__ __launch_bounds__(256) void act_kernel(const float* __restrict__ x,
                                                  const float* __restrict__ grid,
                                                  bf16* __restrict__ A) {
    int t  = blockIdx.x * 256 + threadIdx.x;     // 1,048,576 threads
    int b  = t >> 8;
    int i0 = (t & 255) << 2;
    f32x4 xv4 = *(const f32x4*)(x + (size_t)b * I_F + i0);

    float g[12];
#pragma unroll
    for (int j = 0; j < 12; ++j) g[j] = grid[j];
    float r1[11], r2[10], r3[9];
#pragma unroll
    for (int j = 0; j < 11; ++j) r1[j] = __builtin_amdgcn_rcpf(g[j + 1] - g[j] + EPSC);
#pragma unroll
    for (int j = 0; j < 10; ++j) r2[j] = __builtin_amdgcn_rcpf(g[j + 2] - g[j] + EPSC);
#pragma unroll
    for (int j = 0; j < 9;  ++j) r3[j] = __builtin_amdgcn_rcpf(g[j + 3] - g[j] + EPSC);

    float sw[4];
    float bs8[4][8];
#pragma unroll
    for (int e = 0; e < 4; ++e) {
        float xv = xv4[e];
        float bas[11];
#pragma unroll
        for (int j = 0; j < 11; ++j)
            bas[j] = (xv >= g[j] && xv < g[j + 1]) ? 1.0f : 0.0f;
#pragma unroll
        for (int j = 0; j < 10; ++j)
            bas[j] = (xv - g[j]) * r1[j] * bas[j] + (g[j + 2] - xv) * r1[j + 1] * bas[j + 1];
#pragma unroll
        for (int j = 0; j < 9; ++j)
            bas[j] = (xv - g[j]) * r2[j] * bas[j] + (g[j + 3] - xv) * r2[j + 1] * bas[j + 1];
#pragma unroll
        for (int j = 0; j < 8; ++j)
            bas[j] = (xv - g[j]) * r3[j] * bas[j] + (g[j + 4] - xv) * r3[j + 1] * bas[j + 1];
#pragma unroll
        for (int k = 0; k < 8; ++k) bs8[e][k] = bas[k];
        float sig = 1.0f / (1.0f + __expf(-xv));
        sw[e] = xv * sig;
    }

    bf16* outp = A + (size_t)b * KDIM + i0;
    *(bf16x4*)(outp) = (bf16x4){(bf16)sw[0], (bf16)sw[1], (bf16)sw[2], (bf16)sw[3]};
#pragma unroll
    for (int k = 0; k < 8; ++k)
        *(bf16x4*)(outp + (size_t)(k + 1) * 1024) =
            (bf16x4){(bf16)bs8[0][k], (bf16)bs8[1][k], (bf16)bs8[2][k], (bf16)bs8[3][k]};
}

// ---------------------------------------------------------------------------
// Kernel 2: Wt[o][j*1024+i] = { base_scaler[i,o], spline_weight[i,o,k]*spline_scaler[i,o] }
// ---------------------------------------------------------------------------
__global__ __launch_bounds__(256) void wprep_kernel(const float* __restrict__ w,
                                                    const float* __restrict__ ss,
                                                    const float* __restrict__ bs,
                                                    bf16* __restrict__ Wt) {
    int g = blockIdx.x * 256 + threadIdx.x;      // 1024 i * 128 o-groups = 131072
    int i  = g & 1023;
    int o0 = (g >> 10) << 3;                     // 8 o per thread
#pragma unroll
    for (int oo = 0; oo < 8; ++oo) {
        int o = o0 + oo;
        size_t io = (size_t)i * 1024 + o;
        float scale = ss[io];
        float base  = bs[io];
        const float* wp = w + io * 8;
        f32x4 w0 = *(const f32x4*)(wp);
        f32x4 w1 = *(const f32x4*)(wp + 4);

        bf16* outp = Wt + (size_t)o * KDIM + i;
        outp[0] = (bf16)base;
#pragma unroll
        for (int k = 0; k < 4; ++k) outp[(size_t)(k + 1) * 1024] = (bf16)(w0[k] * scale);
#pragma unroll
        for (int k = 0; k < 4; ++k) outp[(size_t)(k + 5) * 1024] = (bf16)(w1[k] * scale);
    }
}

// ---------------------------------------------------------------------------
// Kernel 3: GEMM  out = A(4096x9216) * Wt^T(1024x9216), bf16 MFMA 32x32x16.
// R11 = R6's proven 86us body VERBATIM: 256x256 tile, 8 waves 2Mx4N, BK=32,
// quad-buffer 128KB LDS, counted vmcnt(8) depth-3, 1 barrier/K-tile, and the
// critical loop-body order {12 frag ds_reads -> stage DMAs -> 16-MFMA
// cluster} (R8/R10's stage-first order cost ~20us, MfmaUtil 40->30).
// Epilogue is now UNIFORM: all splits write bf16 partials (no branch).
// ---------------------------------------------------------------------------
__device__ __forceinline__ void load_lds16(const bf16* g, bf16* l) {
    __builtin_amdgcn_global_load_lds(
        (__attribute__((address_space(1))) void*)g,
        (__attribute__((address_space(3))) void*)l, 16, 0, 0);
}

__global__ __launch_bounds__(512, 2) void gemm_kernel(const bf16* __restrict__ A,
                                                      const bf16* __restrict__ Wt,
                                                      bf16* __restrict__ parts,
                                                      int split, int ktiles) {  // BK=32 units
    __shared__ __align__(16) bf16 SA[4][8192];   // 4 slots x 16KB (256 rows x 32 k)
    __shared__ __align__(16) bf16 SB[4][8192];

    const int t    = threadIdx.x;
    const int lane = t & 63;
    const int w    = t >> 6;           // 0..7

    // XCD-chunked decode: each XCD owns a contiguous L-range sharing tn panels.
    const int nwg8 = gridDim.x >> 3;
    const int L    = (blockIdx.x & 7) * nwg8 + (blockIdx.x >> 3);
    const int nper = split << 4;
    const int tn   = L / nper;
    const int rem  = L - tn * nper;
    const int s    = rem >> 4;
    const int tm   = rem & 15;

    const int row0 = tm << 8;
    const int col0 = tn << 8;
    const size_t k0 = (size_t)s * ktiles * 32;

    // ---- staging (linear LDS dest; pre-swizzled global source) ----
    // content(phys unit p, row r) = logical unit p ^ ((r>>1)&3)
    const int sr = lane >> 2;                         // 0..15
    const int lc = (lane & 3) ^ ((lane >> 3) & 3);    // pre-swizzled 16B-unit
    const bf16* gA0 = A  + (size_t)(row0 + w * 16 + sr) * KDIM + k0 + lc * 8;
    const bf16* gB0 = Wt + (size_t)(col0 + w * 16 + sr) * KDIM + k0 + lc * 8;

    // ---- fragment read coords ----
    const int wm  = w >> 2;            // 0..1  (M half: 128 rows)
    const int wn  = w & 3;             // 0..3  (N quarter: 64 cols)
    const int r31 = lane & 31;
    const int hi  = lane >> 5;
    const int swb = (r31 >> 1) & 3;    // read-side swizzle (row bits 1-2)

    f32x16 acc[4][2];
#pragma unroll
    for (int mt = 0; mt < 4; ++mt)
#pragma unroll
        for (int nt = 0; nt < 2; ++nt)
#pragma unroll
            for (int r = 0; r < 16; ++r) acc[mt][nt][r] = 0.f;

    auto stage = [&](int j) {
        const int sl = j & 3;
        const bf16* pa = gA0 + (size_t)j * 32;
        const bf16* pb = gB0 + (size_t)j * 32;
        load_lds16(pa,                      &SA[sl][w * 512]);
        load_lds16(pa + (size_t)128 * KDIM, &SA[sl][4096 + w * 512]);
        load_lds16(pb,                      &SB[sl][w * 512]);
        load_lds16(pb + (size_t)128 * KDIM, &SB[sl][4096 + w * 512]);
    };

    auto frag_load = [&](int sl, bf16x8 (&af)[4][2], bf16x8 (&bfv)[2][2]) {
#pragma unroll
        for (int mt = 0; mt < 4; ++mt)
#pragma unroll
            for (int ks = 0; ks < 2; ++ks)
                af[mt][ks] = *(const bf16x8*)&SA[sl][(wm * 128 + mt * 32 + r31) * 32
                                                    + (((ks * 2 + hi) ^ swb) << 3)];
#pragma unroll
        for (int nt = 0; nt < 2; ++nt)
#pragma unroll
            for (int ks = 0; ks < 2; ++ks)
                bfv[nt][ks] = *(const bf16x8*)&SB[sl][(wn * 64 + nt * 32 + r31) * 32
                                                     + (((ks * 2 + hi) ^ swb) << 3)];
    };

    auto do_mfma = [&](bf16x8 (&af)[4][2], bf16x8 (&bfv)[2][2]) {
        __builtin_amdgcn_s_setprio(1);
#pragma unroll
        for (int ks = 0; ks < 2; ++ks)
#pragma unroll
            for (int mt = 0; mt < 4; ++mt)
#pragma unroll
                for (int nt = 0; nt < 2; ++nt)
                    acc[mt][nt] = __builtin_amdgcn_mfma_f32_32x32x16_bf16(
                        af[mt][ks], bfv[nt][ks], acc[mt][nt], 0, 0, 0);
        __builtin_amdgcn_s_setprio(0);
    };

    // Prologue: 3 K-tiles in flight.
    stage(0); stage(1); stage(2);

    int j = 0;
    for (; j < ktiles - 3; ++j) {
        asm volatile("s_waitcnt vmcnt(8)" ::: "memory");   // tile j landed
        __builtin_amdgcn_s_barrier();                      // all waves see tile j
        asm volatile("" ::: "memory");                     // no read hoist above bar
        bf16x8 af[4][2], bfv[2][2];
        frag_load(j & 3, af, bfv);                         // reads issued FIRST
        stage(j + 3);                                      // then prefetch DMAs
        do_mfma(af, bfv);                                  // compiler interleaves
    }
    {
        asm volatile("s_waitcnt vmcnt(8)" ::: "memory");
        __builtin_amdgcn_s_barrier();
        asm volatile("" ::: "memory");
        bf16x8 af[4][2], bfv[2][2];
        frag_load(j & 3, af, bfv);
        do_mfma(af, bfv);
        ++j;
    }
    {
        asm volatile("s_waitcnt vmcnt(4)" ::: "memory");
        __builtin_amdgcn_s_barrier();
        asm volatile("" ::: "memory");
        bf16x8 af[4][2], bfv[2][2];
        frag_load(j & 3, af, bfv);
        do_mfma(af, bfv);
        ++j;
    }
    {
        asm volatile("s_waitcnt vmcnt(0)" ::: "memory");
        __builtin_amdgcn_s_barrier();
        asm volatile("" ::: "memory");
        bf16x8 af[4][2], bfv[2][2];
        frag_load(j & 3, af, bfv);
        do_mfma(af, bfv);
    }

    // Epilogue (UNIFORM, no branch): bf16 partial for every split s.
    // 32x32 C/D layout: col=lane&31, row=(reg&3)+8*(reg>>2)+4*(lane>>5) [m74/m101]
    bf16* cp = parts + (size_t)s * BATCH * O_F
             + (size_t)(row0 + wm * 128) * O_F + col0 + wn * 64 + r31;
#pragma unroll
    for (int mt = 0; mt < 4; ++mt)
#pragma unroll
        for (int nt = 0; nt < 2; ++nt)
#pragma unroll
            for (int r = 0; r < 16; ++r) {
                int rl = (r & 3) + 8 * (r >> 2) + 4 * hi;
                cp[(size_t)(mt * 32 + rl) * O_F + nt * 32] = (bf16)acc[mt][nt][r];
            }
}

// ---------------------------------------------------------------------------
// Kernel 4: out = sum(parts[0..np))   (split-K reduce), bf16 partials -> f32
// ---------------------------------------------------------------------------
__global__ __launch_bounds__(256) void add_kernel(float* __restrict__ out,
                                                  const bf16* __restrict__ parts,
                                                  int np) {
    int t = blockIdx.x * 256 + threadIdx.x;      // 1,048,576 threads, 4 f32 each
    f32x4 a = {0.f, 0.f, 0.f, 0.f};
    for (int p = 0; p < np; ++p) {
        bf16x4 b = *((const bf16x4*)(parts + (size_t)p * BATCH * O_F) + t);
#pragma unroll
        for (int e = 0; e < 4; ++e) a[e] += (float)b[e];
    }
    *((f32x4*)out + t) = a;
}

// ---------------------------------------------------------------------------
extern "C" void kernel_launch(void* const* d_in, const int* in_sizes, int n_in,
                              void* d_out, int out_size, void* d_ws, size_t ws_size,
                              hipStream_t stream) {
    const float* x    = (const float*)d_in[0];
    const float* grid = (const float*)d_in[1];
    const float* w    = (const float*)d_in[2];
    const float* ss   = (const float*)d_in[3];
    const float* bs   = (const float*)d_in[4];
    float* out = (float*)d_out;

    const size_t nA = (size_t)BATCH * KDIM * 2;   // 75.5 MB
    const size_t nW = (size_t)O_F   * KDIM * 2;   // 18.9 MB
    const size_t nP = (size_t)BATCH * O_F  * 2;   // 8.39 MB per bf16 partial

    bf16* A  = (bf16*)d_ws;
    bf16* Wt = (bf16*)((char*)d_ws + nA);
    bf16* parts = (bf16*)((char*)d_ws + nA + nW);

    act_kernel<<<(BATCH * I_F / 4) / 256, 256, 0, stream>>>(x, grid, A);
    wprep_kernel<<<(I_F * O_F / 8) / 256, 256, 0, stream>>>(w, ss, bs, Wt);

    int split = (ws_size >= nA + nW + 4 * nP) ? 4
              : (ws_size >= nA + nW + 2 * nP) ? 2 : 1;
    gemm_kernel<<<64 * split, 512, 0, stream>>>(A, Wt, parts, split, 288 / split);
    add_kernel<<<(BATCH * O_F / 4) / 256, 256, 0, stream>>>(out, parts, split);
}

// Round 12
// 126.646 us; speedup vs baseline: 1.1672x; 1.0191x over previous
//
#include <hip/hip_runtime.h>
#include <hip/hip_bf16.h>
#include <cstdint>
#include <cstddef>

#define I_F   1024
#define O_F   1024
#define BATCH 4096
#define KDIM  9216   // 9 * 1024 : j-major (j=0 base/swish, j=1..8 spline bases)
#define EPSC  1e-7f

typedef __bf16 bf16;
typedef __bf16 bf16x4 __attribute__((ext_vector_type(4)));
typedef __bf16 bf16x8 __attribute__((ext_vector_type(8)));
typedef float  f32x4  __attribute__((ext_vector_type(4)));
typedef float  f32x16 __attribute__((ext_vector_type(16)));

// ---------------------------------------------------------------------------
// Kernel 1: activations A[b][j*1024+i] = {swish(x), bases[0..7]}  (bf16)
// ---------------------------------------------------------------------------
__global__ __launch_bounds__(256) void act_kernel(const float* __restrict__ x,
                                                  const float* __restrict__ grid,
                                                  bf16* __restrict__ A) {
    int t  = blockIdx.x * 256 + threadIdx.x;     // 1,048,576 threads
    int b  = t >> 8;
    int i0 = (t & 255) << 2;
    f32x4 xv4 = *(const f32x4*)(x + (size_t)b * I_F + i0);

    float g[12];
#pragma unroll
    for (int j = 0; j < 12; ++j) g[j] = grid[j];
    float r1[11], r2[10], r3[9];
#pragma unroll
    for (int j = 0; j < 11; ++j) r1[j] = __builtin_amdgcn_rcpf(g[j + 1] - g[j] + EPSC);
#pragma unroll
    for (int j = 0; j < 10; ++j) r2[j] = __builtin_amdgcn_rcpf(g[j + 2] - g[j] + EPSC);
#pragma unroll
    for (int j = 0; j < 9;  ++j) r3[j] = __builtin_amdgcn_rcpf(g[j + 3] - g[j] + EPSC);

    float sw[4];
    float bs8[4][8];
#pragma unroll
    for (int e = 0; e < 4; ++e) {
        float xv = xv4[e];
        float bas[11];
#pragma unroll
        for (int j = 0; j < 11; ++j)
            bas[j] = (xv >= g[j] && xv < g[j + 1]) ? 1.0f : 0.0f;
#pragma unroll
        for (int j = 0; j < 10; ++j)
            bas[j] = (xv - g[j]) * r1[j] * bas[j] + (g[j + 2] - xv) * r1[j + 1] * bas[j + 1];
#pragma unroll
        for (int j = 0; j < 9; ++j)
            bas[j] = (xv - g[j]) * r2[j] * bas[j] + (g[j + 3] - xv) * r2[j + 1] * bas[j + 1];
#pragma unroll
        for (int j = 0; j < 8; ++j)
            bas[j] = (xv - g[j]) * r3[j] * bas[j] + (g[j + 4] - xv) * r3[j + 1] * bas[j + 1];
#pragma unroll
        for (int k = 0; k < 8; ++k) bs8[e][k] = bas[k];
        float sig = 1.0f / (1.0f + __expf(-xv));
        sw[e] = xv * sig;
    }

    bf16* outp = A + (size_t)b * KDIM + i0;
    *(bf16x4*)(outp) = (bf16x4){(bf16)sw[0], (bf16)sw[1], (bf16)sw[2], (bf16)sw[3]};
#pragma unroll
    for (int k = 0; k < 8; ++k)
        *(bf16x4*)(outp + (size_t)(k + 1) * 1024) =
            (bf16x4){(bf16)bs8[0][k], (bf16)bs8[1][k], (bf16)bs8[2][k], (bf16)bs8[3][k]};
}

// ---------------------------------------------------------------------------
// Kernel 2: Wt[o][j*1024+i] = { base_scaler[i,o], spline_weight[i,o,k]*spline_scaler[i,o] }
// ss/bs loads vectorized (32B contiguous per thread).
// ---------------------------------------------------------------------------
__global__ __launch_bounds__(256) void wprep_kernel(const float* __restrict__ w,
                                                    const float* __restrict__ ss,
                                                    const float* __restrict__ bs,
                                                    bf16* __restrict__ Wt) {
    int g = blockIdx.x * 256 + threadIdx.x;      // 1024 i * 128 o-groups = 131072
    int i  = g & 1023;
    int o0 = (g >> 10) << 3;                     // 8 o per thread
    size_t io0 = (size_t)i * 1024 + o0;
    f32x4 ssv0 = *(const f32x4*)(ss + io0);
    f32x4 ssv1 = *(const f32x4*)(ss + io0 + 4);
    f32x4 bsv0 = *(const f32x4*)(bs + io0);
    f32x4 bsv1 = *(const f32x4*)(bs + io0 + 4);
#pragma unroll
    for (int oo = 0; oo < 8; ++oo) {
        int o = o0 + oo;
        float scale = (oo < 4) ? ssv0[oo & 3] : ssv1[oo & 3];
        float base  = (oo < 4) ? bsv0[oo & 3] : bsv1[oo & 3];
        const float* wp = w + (io0 + oo) * 8;
        f32x4 w0 = *(const f32x4*)(wp);
        f32x4 w1 = *(const f32x4*)(wp + 4);

        bf16* outp = Wt + (size_t)o * KDIM + i;
        outp[0] = (bf16)base;
#pragma unroll
        for (int k = 0; k < 4; ++k) outp[(size_t)(k + 1) * 1024] = (bf16)(w0[k] * scale);
#pragma unroll
        for (int k = 0; k < 4; ++k) outp[(size_t)(k + 5) * 1024] = (bf16)(w1[k] * scale);
    }
}

// ---------------------------------------------------------------------------
// Kernel 3: GEMM  out = A(4096x9216) * Wt^T(1024x9216), bf16 MFMA 32x32x16.
// R12 = R11 byte-identical EXCEPT the frag read issue order: reads are
// issued in MFMA-need order (ks-major, A/B interleaved:
// af0,bv0,af1,bv1,af2,af3 per ks). ds_read results return IN ORDER per
// wave, so R11's mt-major order made the first MFMA wait on read #9/12;
// now its operands are reads #1-2 -> MFMA cluster overlaps the read window.
// ---------------------------------------------------------------------------
__device__ __forceinline__ void load_lds16(const bf16* g, bf16* l) {
    __builtin_amdgcn_global_load_lds(
        (__attribute__((address_space(1))) void*)g,
        (__attribute__((address_space(3))) void*)l, 16, 0, 0);
}

__global__ __launch_bounds__(512, 2) void gemm_kernel(const bf16* __restrict__ A,
                                                      const bf16* __restrict__ Wt,
                                                      bf16* __restrict__ parts,
                                                      int split, int ktiles) {  // BK=32 units
    __shared__ __align__(16) bf16 SA[4][8192];   // 4 slots x 16KB (256 rows x 32 k)
    __shared__ __align__(16) bf16 SB[4][8192];

    const int t    = threadIdx.x;
    const int lane = t & 63;
    const int w    = t >> 6;           // 0..7

    // XCD-chunked decode: each XCD owns a contiguous L-range sharing tn panels.
    const int nwg8 = gridDim.x >> 3;
    const int L    = (blockIdx.x & 7) * nwg8 + (blockIdx.x >> 3);
    const int nper = split << 4;
    const int tn   = L / nper;
    const int rem  = L - tn * nper;
    const int s    = rem >> 4;
    const int tm   = rem & 15;

    const int row0 = tm << 8;
    const int col0 = tn << 8;
    const size_t k0 = (size_t)s * ktiles * 32;

    // ---- staging (linear LDS dest; pre-swizzled global source) ----
    // content(phys unit p, row r) = logical unit p ^ ((r>>1)&3)
    const int sr = lane >> 2;                         // 0..15
    const int lc = (lane & 3) ^ ((lane >> 3) & 3);    // pre-swizzled 16B-unit
    const bf16* gA0 = A  + (size_t)(row0 + w * 16 + sr) * KDIM + k0 + lc * 8;
    const bf16* gB0 = Wt + (size_t)(col0 + w * 16 + sr) * KDIM + k0 + lc * 8;

    // ---- fragment read coords ----
    const int wm  = w >> 2;            // 0..1  (M half: 128 rows)
    const int wn  = w & 3;             // 0..3  (N quarter: 64 cols)
    const int r31 = lane & 31;
    const int hi  = lane >> 5;
    const int swb = (r31 >> 1) & 3;    // read-side swizzle (row bits 1-2)

    f32x16 acc[4][2];
#pragma unroll
    for (int mt = 0; mt < 4; ++mt)
#pragma unroll
        for (int nt = 0; nt < 2; ++nt)
#pragma unroll
            for (int r = 0; r < 16; ++r) acc[mt][nt][r] = 0.f;

    auto stage = [&](int j) {
        const int sl = j & 3;
        const bf16* pa = gA0 + (size_t)j * 32;
        const bf16* pb = gB0 + (size_t)j * 32;
        load_lds16(pa,                      &SA[sl][w * 512]);
        load_lds16(pa + (size_t)128 * KDIM, &SA[sl][4096 + w * 512]);
        load_lds16(pb,                      &SB[sl][w * 512]);
        load_lds16(pb + (size_t)128 * KDIM, &SB[sl][4096 + w * 512]);
    };

    // Reads issued in MFMA-need order for one ks slice.
    auto frag_load_ks = [&](int sl, int ks, bf16x8 (&af)[4], bf16x8 (&bv)[2]) {
        const int cp = ((ks * 2 + hi) ^ swb) << 3;
        af[0] = *(const bf16x8*)&SA[sl][(wm * 128 +  0 + r31) * 32 + cp];
        bv[0] = *(const bf16x8*)&SB[sl][(wn * 64  +  0 + r31) * 32 + cp];
        af[1] = *(const bf16x8*)&SA[sl][(wm * 128 + 32 + r31) * 32 + cp];
        bv[1] = *(const bf16x8*)&SB[sl][(wn * 64  + 32 + r31) * 32 + cp];
        af[2] = *(const bf16x8*)&SA[sl][(wm * 128 + 64 + r31) * 32 + cp];
        af[3] = *(const bf16x8*)&SA[sl][(wm * 128 + 96 + r31) * 32 + cp];
    };

    auto do_mfma = [&](bf16x8 (&af0)[4], bf16x8 (&bv0)[2],
                       bf16x8 (&af1)[4], bf16x8 (&bv1)[2]) {
        __builtin_amdgcn_s_setprio(1);
#pragma unroll
        for (int mt = 0; mt < 4; ++mt)
#pragma unroll
            for (int nt = 0; nt < 2; ++nt)
                acc[mt][nt] = __builtin_amdgcn_mfma_f32_32x32x16_bf16(
                    af0[mt], bv0[nt], acc[mt][nt], 0, 0, 0);
#pragma unroll
        for (int mt = 0; mt < 4; ++mt)
#pragma unroll
            for (int nt = 0; nt < 2; ++nt)
                acc[mt][nt] = __builtin_amdgcn_mfma_f32_32x32x16_bf16(
                    af1[mt], bv1[nt], acc[mt][nt], 0, 0, 0);
        __builtin_amdgcn_s_setprio(0);
    };

    // Prologue: 3 K-tiles in flight.
    stage(0); stage(1); stage(2);

    int j = 0;
    for (; j < ktiles - 3; ++j) {
        asm volatile("s_waitcnt vmcnt(8)" ::: "memory");   // tile j landed
        __builtin_amdgcn_s_barrier();                      // all waves see tile j
        asm volatile("" ::: "memory");                     // no read hoist above bar
        bf16x8 af0[4], bv0[2], af1[4], bv1[2];
        frag_load_ks(j & 3, 0, af0, bv0);                  // ks0 reads first (need-order)
        frag_load_ks(j & 3, 1, af1, bv1);                  // then ks1 reads
        stage(j + 3);                                      // then prefetch DMAs
        do_mfma(af0, bv0, af1, bv1);                       // compiler interleaves
    }
    {
        asm volatile("s_waitcnt vmcnt(8)" ::: "memory");
        __builtin_amdgcn_s_barrier();
        asm volatile("" ::: "memory");
        bf16x8 af0[4], bv0[2], af1[4], bv1[2];
        frag_load_ks(j & 3, 0, af0, bv0);
        frag_load_ks(j & 3, 1, af1, bv1);
        do_mfma(af0, bv0, af1, bv1);
        ++j;
    }
    {
        asm volatile("s_waitcnt vmcnt(4)" ::: "memory");
        __builtin_amdgcn_s_barrier();
        asm volatile("" ::: "memory");
        bf16x8 af0[4], bv0[2], af1[4], bv1[2];
        frag_load_ks(j & 3, 0, af0, bv0);
        frag_load_ks(j & 3, 1, af1, bv1);
        do_mfma(af0, bv0, af1, bv1);
        ++j;
    }
    {
        asm volatile("s_waitcnt vmcnt(0)" ::: "memory");
        __builtin_amdgcn_s_barrier();
        asm volatile("" ::: "memory");
        bf16x8 af0[4], bv0[2], af1[4], bv1[2];
        frag_load_ks(j & 3, 0, af0, bv0);
        frag_load_ks(j & 3, 1, af1, bv1);
        do_mfma(af0, bv0, af1, bv1);
    }

    // Epilogue (UNIFORM): bf16 partial for every split s.
    // 32x32 C/D layout: col=lane&31, row=(reg&3)+8*(reg>>2)+4*(lane>>5) [m74/m101]
    bf16* cp = parts + (size_t)s * BATCH * O_F
             + (size_t)(row0 + wm * 128) * O_F + col0 + wn * 64 + r31;
#pragma unroll
    for (int mt = 0; mt < 4; ++mt)
#pragma unroll
        for (int nt = 0; nt < 2; ++nt)
#pragma unroll
            for (int r = 0; r < 16; ++r) {
                int rl = (r & 3) + 8 * (r >> 2) + 4 * hi;
                cp[(size_t)(mt * 32 + rl) * O_F + nt * 32] = (bf16)acc[mt][nt][r];
            }
}

// ---------------------------------------------------------------------------
// Kernel 4: out = sum(parts[0..np))   (split-K reduce), bf16 partials -> f32
// ---------------------------------------------------------------------------
__global__ __launch_bounds__(256) void add_kernel(float* __restrict__ out,
                                                  const bf16* __restrict__ parts,
                                                  int np) {
    int t = blockIdx.x * 256 + threadIdx.x;      // 1,048,576 threads, 4 f32 each
    f32x4 a = {0.f, 0.f, 0.f, 0.f};
    for (int p = 0; p < np; ++p) {
        bf16x4 b = *((const bf16x4*)(parts + (size_t)p * BATCH * O_F) + t);
#pragma unroll
        for (int e = 0; e < 4; ++e) a[e] += (float)b[e];
    }
    *((f32x4*)out + t) = a;
}

// ---------------------------------------------------------------------------
extern "C" void kernel_launch(void* const* d_in, const int* in_sizes, int n_in,
                              void* d_out, int out_size, void* d_ws, size_t ws_size,
                              hipStream_t stream) {
    const float* x    = (const float*)d_in[0];
    const float* grid = (const float*)d_in[1];
    const float* w    = (const float*)d_in[2];
    const float* ss   = (const float*)d_in[3];
    const float* bs   = (const float*)d_in[4];
    float* out = (float*)d_out;

    const size_t nA = (size_t)BATCH * KDIM * 2;   // 75.5 MB
    const size_t nW = (size_t)O_F   * KDIM * 2;   // 18.9 MB
    const size_t nP = (size_t)BATCH * O_F  * 2;   // 8.39 MB per bf16 partial

    bf16* A  = (bf16*)d_ws;
    bf16* Wt = (bf16*)((char*)d_ws + nA);
    bf16* parts = (bf16*)((char*)d_ws + nA + nW);

    act_kernel<<<(BATCH * I_F / 4) / 256, 256, 0, stream>>>(x, grid, A);
    wprep_kernel<<<(I_F * O_F / 8) / 256, 256, 0, stream>>>(w, ss, bs, Wt);

    int split = (ws_size >= nA + nW + 4 * nP) ? 4
              : (ws_size >= nA + nW + 2 * nP) ? 2 : 1;
    gemm_kernel<<<64 * split, 512, 0, stream>>>(A, Wt, parts, split, 288 / split);
    add_kernel<<<(BATCH * O_F / 4) / 256, 256, 0, stream>>>(out, parts, split);
}